// Round 3
// baseline (229.197 us; speedup 1.0000x reference)
//
#include <hip/hip_runtime.h>
#include <hip/hip_bf16.h>

// AugmentedTripletLoss on MI355X.
// inputs [8192,128] f32, targets [8192] int, center [16,128] f32 -> scalar loss.
//
// v3: two launches.
//  prep:     per-block center normalization (redundant, cheap) + per-row sq,
//            bf16 pack, mindc; inits encoded atomic-merge arrays + ticket.
//  pairdist: 2048 blocks (128 row-groups x 16 strips). Each wave stages its
//            private 16-col B tile through LDS (coalesced global uint4 ->
//            ds_write_b128 swizzled -> ds_read_b128), no K-loop barriers,
//            depth-2 prefetch. MFMA C init = -sq_c/2 so w = dot - sq_c/2;
//            dist2 = sq_r - 2w (monotone -> defer sqrt). Per-row min/max of w
//            merged via ordered-uint atomicMin/Max; last block (atomic ticket)
//            computes the loss.

#define N_ROWS 8192
#define NPROTO 16
#define MARGIN_F 1.0f
#define EPS_F 1e-12f
#define NBLK_PD 2048
#define ENCP_INIT 0xFF800000u  // enc(+inf)
#define ENCN_INIT 0x007FFFFFu  // enc(-inf)

typedef __attribute__((ext_vector_type(8))) short short8;   // 8 bf16 = 4 VGPRs
typedef __attribute__((ext_vector_type(4))) float float4v;  // MFMA acc

static __device__ __forceinline__ unsigned f2bf(float f) {
  unsigned u = __float_as_uint(f);
  u += 0x7fffu + ((u >> 16) & 1u);  // RNE
  return u >> 16;
}
// order-preserving float<->uint for atomicMin/Max
static __device__ __forceinline__ unsigned encf(float f) {
  unsigned u = __float_as_uint(f);
  return (u & 0x80000000u) ? ~u : (u | 0x80000000u);
}
static __device__ __forceinline__ float decf(unsigned e) {
  unsigned u = (e & 0x80000000u) ? (e ^ 0x80000000u) : ~e;
  return __uint_as_float(u);
}

__global__ void prep_kernel(const float* __restrict__ x,
                            const float* __restrict__ center,
                            uint4* __restrict__ xbf4, float* __restrict__ sq,
                            float* __restrict__ mindc,
                            unsigned* __restrict__ pposU,
                            unsigned* __restrict__ pnegU,
                            unsigned* __restrict__ counter) {
  __shared__ float scn[NPROTO * 128];  // raw centers, 8 KB
  __shared__ float sinv[NPROTO];       // 1/||center_p||
  int tid = threadIdx.x;
#pragma unroll
  for (int j = 0; j < 8; ++j) scn[j * 256 + tid] = center[j * 256 + tid];
  __syncthreads();
  int rloc = tid >> 4, l = tid & 15;
  {  // center norms (every block redundantly; 2k FLOP)
    const float* c = &scn[rloc * 128 + l * 8];
    float ss = 0.f;
#pragma unroll
    for (int j = 0; j < 8; ++j) ss += c[j] * c[j];
#pragma unroll
    for (int m = 1; m < 16; m <<= 1) ss += __shfl_xor(ss, m, 64);
    if (l == 0) sinv[rloc] = 1.0f / sqrtf(ss);
  }
  __syncthreads();
  int row = blockIdx.x * 16 + rloc;
  float4 v0 = ((const float4*)x)[row * 32 + l * 2];
  float4 v1 = ((const float4*)x)[row * 32 + l * 2 + 1];
  float ss = v0.x * v0.x + v0.y * v0.y + v0.z * v0.z + v0.w * v0.w +
             v1.x * v1.x + v1.y * v1.y + v1.z * v1.z + v1.w * v1.w;
  float dots[NPROTO];
#pragma unroll
  for (int p = 0; p < NPROTO; ++p) {
    const float* c = &scn[p * 128 + l * 8];
    dots[p] = v0.x * c[0] + v0.y * c[1] + v0.z * c[2] + v0.w * c[3] +
              v1.x * c[4] + v1.y * c[5] + v1.z * c[6] + v1.w * c[7];
  }
#pragma unroll
  for (int m = 1; m < 16; m <<= 1) {
    ss += __shfl_xor(ss, m, 64);
#pragma unroll
    for (int p = 0; p < NPROTO; ++p) dots[p] += __shfl_xor(dots[p], m, 64);
  }
  uint4 pk;
  pk.x = f2bf(v0.x) | (f2bf(v0.y) << 16);
  pk.y = f2bf(v0.z) | (f2bf(v0.w) << 16);
  pk.z = f2bf(v1.x) | (f2bf(v1.y) << 16);
  pk.w = f2bf(v1.z) | (f2bf(v1.w) << 16);
  xbf4[row * 16 + l] = pk;  // row-major bf16, 256 B/row
  if (l == 0) {
    float mind2 = INFINITY;
#pragma unroll
    for (int p = 0; p < NPROTO; ++p)
      mind2 = fminf(mind2, ss + 1.0f - 2.0f * dots[p] * sinv[p]);
    sq[row] = ss;
    mindc[row] = fmaxf(sqrtf(fmaxf(mind2, 0.0f)), EPS_F);
  }
  // init merge arrays + ticket (stream-ordered before pairdist)
  if (tid < 16) pposU[blockIdx.x * 16 + tid] = ENCP_INIT;
  else if (tid < 32) pnegU[blockIdx.x * 16 + tid - 16] = ENCN_INIT;
  if (blockIdx.x == 0 && tid == 32) *counter = 0u;
}

__global__ __launch_bounds__(256) void
pairdist_kernel(const char* __restrict__ xbf, const float* __restrict__ sq,
                const int* __restrict__ tgt, const float* __restrict__ mindc,
                unsigned* __restrict__ pposU, unsigned* __restrict__ pnegU,
                unsigned* __restrict__ counter, float* __restrict__ out) {
  __shared__ char bstage[4][2][4096];  // per-wave private double buffer, 32 KB
  __shared__ float smrg[2][4][64];     // cross-wave merge, 2 KB
  __shared__ float bsum[4];
  __shared__ int islast;
  int bid = blockIdx.x;
  int rg = bid >> 4, strip = bid & 15;
  int wave = threadIdx.x >> 6, lane = threadIdx.x & 63;
  int q = lane >> 4, l16 = lane & 15;
  int rowbase = rg * 64;
  int colS = strip * 512 + wave * 16;  // wave's cols for tile t: colS + t*64 + [0,16)

  // A frags for all 64 block rows: A[m=l16][k=q*8+j], K=128 over 4 kc chunks
  short8 a[4][4];
#pragma unroll
  for (int rt = 0; rt < 4; ++rt) {
    const char* ar = xbf + (size_t)(rowbase + rt * 16 + l16) * 256 + q * 16;
#pragma unroll
    for (int kc = 0; kc < 4; ++kc) a[rt][kc] = *(const short8*)(ar + kc * 64);
  }
  // packed row targets (targets < 64 -> 1 byte each): byte r of trp[rt] = tgt[rowbase+rt*16+q*4+r]
  int trp[4];
#pragma unroll
  for (int rt = 0; rt < 4; ++rt) {
    int4 tv = ((const int4*)tgt)[(rowbase >> 2) + rt * 4 + q];
    trp[rt] = tv.x | (tv.y << 8) | (tv.z << 16) | (tv.w << 24);
  }
  // LDS offsets. XOR swizzle: chunk c of row r stored at (r, c^r) -> ~2-way banks.
  int swoff[4], rdoff[4];
#pragma unroll
  for (int rr = 0; rr < 4; ++rr) {
    int r = rr * 4 + q;  // staging row this lane writes in round rr (source chunk = l16)
    swoff[rr] = r * 256 + (((l16 ^ r) & 15) << 4);
    rdoff[rr] = l16 * 256 + ((((rr * 4 + q) ^ l16) & 15) << 4);  // frag chunk kc*4+q of row l16
  }
  const char* gb = xbf + (size_t)colS * 256;  // +t*16384 per tile
  char* myb0 = &bstage[wave][0][0];
  char* myb1 = &bstage[wave][1][0];

  uint4 rnext[4];
#pragma unroll
  for (int rr = 0; rr < 4; ++rr)  // tile 0 -> regs -> buf0
    rnext[rr] = *(const uint4*)(gb + rr * 1024 + lane * 16);
#pragma unroll
  for (int rr = 0; rr < 4; ++rr) *(uint4*)(myb0 + swoff[rr]) = rnext[rr];
#pragma unroll
  for (int rr = 0; rr < 4; ++rr)  // tile 1 -> regs
    rnext[rr] = *(const uint4*)(gb + 16384 + rr * 1024 + lane * 16);
  float sq0 = sq[colS + l16];
  int tg0 = tgt[colS + l16] & 255;
  float sq1 = sq[colS + 64 + l16];
  int tg1 = tgt[colS + 64 + l16] & 255;

  float wpmin[16], wnmax[16];
#pragma unroll
  for (int i = 0; i < 16; ++i) { wpmin[i] = INFINITY; wnmax[i] = -INFINITY; }

#pragma unroll
  for (int t = 0; t < 8; ++t) {
    char* bufc = (t & 1) ? myb1 : myb0;
    char* bufn = (t & 1) ? myb0 : myb1;
    // 1) read current tile's B frags (prior-iter write already drained)
    short8 b[4];
#pragma unroll
    for (int kc = 0; kc < 4; ++kc) b[kc] = *(const short8*)(bufc + rdoff[kc]);
    // 2) write tile t+1 (vmcnt wait lands here, one iteration after issue)
    if (t < 7) {
#pragma unroll
      for (int rr = 0; rr < 4; ++rr) *(uint4*)(bufn + swoff[rr]) = rnext[rr];
    }
    // 3) issue coalesced loads for tile t+2
    if (t < 6) {
      const char* g2 = gb + (t + 2) * 16384;
#pragma unroll
      for (int rr = 0; rr < 4; ++rr)
        rnext[rr] = *(const uint4*)(g2 + rr * 1024 + lane * 16);
    }
    // 4) MFMA with C init = -sq_c/2  ->  acc = dot - sq_c/2 = w
    float cini = -0.5f * sq0;
    float4v acc[4];
#pragma unroll
    for (int rt = 0; rt < 4; ++rt) acc[rt] = (float4v){cini, cini, cini, cini};
#pragma unroll
    for (int kc = 0; kc < 4; ++kc)
#pragma unroll
      for (int rt = 0; rt < 4; ++rt)
        acc[rt] = __builtin_amdgcn_mfma_f32_16x16x32_bf16(a[rt][kc], b[kc],
                                                          acc[rt], 0, 0, 0);
    int tcur = tg0;
    sq0 = sq1; tg0 = tg1;
    if (t < 6) {
      sq1 = sq[colS + (t + 2) * 64 + l16];
      tg1 = tgt[colS + (t + 2) * 64 + l16] & 255;
    }
    // 5) epilogue: dist2 = sq_r - 2w -> max dist == min w (same), min dist == max w (diff)
#pragma unroll
    for (int rt = 0; rt < 4; ++rt) {
#pragma unroll
      for (int r = 0; r < 4; ++r) {
        int tb = (trp[rt] >> (8 * r)) & 255;
        float w = acc[rt][r];
        bool s = (tcur == tb);
        int idx = rt * 4 + r;
        wpmin[idx] = fminf(wpmin[idx], s ? w : INFINITY);
        wnmax[idx] = fmaxf(wnmax[idx], s ? -INFINITY : w);
      }
    }
  }
  // reduce across the 16 lanes of each quad
#pragma unroll
  for (int m = 1; m < 16; m <<= 1) {
#pragma unroll
    for (int i = 0; i < 16; ++i) {
      wpmin[i] = fminf(wpmin[i], __shfl_xor(wpmin[i], m, 64));
      wnmax[i] = fmaxf(wnmax[i], __shfl_xor(wnmax[i], m, 64));
    }
  }
  if (l16 == 0) {
#pragma unroll
    for (int rt = 0; rt < 4; ++rt)
#pragma unroll
      for (int r = 0; r < 4; ++r) {
        smrg[0][wave][rt * 16 + q * 4 + r] = wpmin[rt * 4 + r];
        smrg[1][wave][rt * 16 + q * 4 + r] = wnmax[rt * 4 + r];
      }
  }
  __syncthreads();
  if (threadIdx.x < 64) {
    int i = threadIdx.x;
    float wp = fminf(fminf(smrg[0][0][i], smrg[0][1][i]),
                     fminf(smrg[0][2][i], smrg[0][3][i]));
    float wn = fmaxf(fmaxf(smrg[1][0][i], smrg[1][1][i]),
                     fmaxf(smrg[1][2][i], smrg[1][3][i]));
    atomicMin(&pposU[rowbase + i], encf(wp));
    atomicMax(&pnegU[rowbase + i], encf(wn));
  }
  __threadfence();  // release our atomics
  __syncthreads();
  if (threadIdx.x == 0) islast = (atomicAdd(counter, 1u) == NBLK_PD - 1u);
  __syncthreads();
  if (!islast) return;
  __threadfence();  // acquire: all blocks' atomics visible
  float lsum = 0.f;
#pragma unroll 4
  for (int k = 0; k < N_ROWS / 256; ++k) {
    int i = k * 256 + threadIdx.x;
    unsigned ep = __hip_atomic_load(&pposU[i], __ATOMIC_RELAXED,
                                    __HIP_MEMORY_SCOPE_AGENT);
    unsigned en = __hip_atomic_load(&pnegU[i], __ATOMIC_RELAXED,
                                    __HIP_MEMORY_SCOPE_AGENT);
    float si = sq[i];
    float dap = sqrtf(fmaxf(fmaf(-2.0f, decf(ep), si), EPS_F));
    float dan = (en == ENCN_INIT)
                    ? (dap + MARGIN_F)
                    : sqrtf(fmaxf(fmaf(-2.0f, decf(en), si), EPS_F));
    dan = fminf(dan, mindc[i]);
    lsum += fmaxf(dap - dan + MARGIN_F, 0.0f);
  }
#pragma unroll
  for (int m = 1; m < 64; m <<= 1) lsum += __shfl_xor(lsum, m, 64);
  if (lane == 0) bsum[wave] = lsum;
  __syncthreads();
  if (threadIdx.x == 0)
    out[0] = (bsum[0] + bsum[1] + bsum[2] + bsum[3]) * (1.0f / (float)N_ROWS);
}

extern "C" void kernel_launch(void* const* d_in, const int* in_sizes, int n_in,
                              void* d_out, int out_size, void* d_ws, size_t ws_size,
                              hipStream_t stream) {
  const float* inputs = (const float*)d_in[0];
  const int* targets = (const int*)d_in[1];
  const float* center = (const float*)d_in[2];
  char* ws = (char*)d_ws;
  uint4* xbf4       = (uint4*)(ws + 0);         // 2 MB bf16 X, 256 B/row
  float* sq         = (float*)(ws + 2097152);   // 32 KB
  float* mindc      = (float*)(ws + 2129920);   // 32 KB
  unsigned* pposU   = (unsigned*)(ws + 2162688);  // 32 KB  enc(min w | same)
  unsigned* pnegU   = (unsigned*)(ws + 2195456);  // 32 KB  enc(max w | diff)
  unsigned* counter = (unsigned*)(ws + 2228224);  // 4 B ticket
  float* out        = (float*)d_out;

  prep_kernel<<<512, 256, 0, stream>>>(inputs, center, xbf4, sq, mindc,
                                       pposU, pnegU, counter);
  pairdist_kernel<<<NBLK_PD, 256, 0, stream>>>((const char*)xbf4, sq, targets,
                                               mindc, pposU, pnegU, counter, out);
}